// Round 5
// baseline (289.682 us; speedup 1.0000x reference)
//
#include <hip/hip_runtime.h>

// MaskedAttentionHead: y = softmax((q@Wq+bq)(k@Wk+bk)^T/8 * m_row) @ (v@Wv+bv)
// B=4 S=4096 D=1024 DK=64. fp32 in/out, bf16 MFMA intermediates, fp32 accum.
// m/8*log2e folded into Q-proj -> mask-free exp2 flash attn, no max-subtract
// (scores statically bounded), additive split-K (4 splits).
// R11: second resubmit of R9 (two container infra failures; kernel never ran;
// source re-audited: bounds/alignment/uniformity all verified safe).
// R9: proj pinned at 79us/1.37TB/s across tile-size, occupancy and coalescing
// changes (R6-R8) -> the barrier-lockstep LDS skeleton is the invariant
// suspect. DK=64 lets both MFMA operands stream straight from global
// (A: 32B/lane contiguous fp32 X; B: 16B/lane contiguous bf16 WT, L2-resident)
// -> rewrite proj with ZERO LDS, ZERO barriers: 1 wave = 16x64 output tile,
// 128 MFMAs, pure streaming. p=2 transposes by swapping MFMA operand roles.

typedef __attribute__((ext_vector_type(8))) short short8;   // 8 bf16 = MFMA A/B frag
typedef __attribute__((ext_vector_type(4))) float float4v;  // MFMA C/D frag
typedef __attribute__((ext_vector_type(4))) unsigned int uint4v;

#define DEV static __device__ __forceinline__

DEV unsigned short f2bf(float f) {
  unsigned int x; __builtin_memcpy(&x, &f, 4);
  x += 0x7fff + ((x >> 16) & 1);  // round-to-nearest-even
  return (unsigned short)(x >> 16);
}

// ---------------- kernel 1: W transpose (3 x [1024,64] -> [64,1024] bf16) ---
__global__ __launch_bounds__(256) void transpose_w(
    const float* __restrict__ Wq, const float* __restrict__ Wk,
    const float* __restrict__ Wv, unsigned short* __restrict__ WT) {
  int idx = blockIdx.x * 256 + threadIdx.x;   // over 3*1024*64
  int p = idx >> 16;
  int r = idx & 65535;            // r = k*64 + d  (coalesced read)
  int kk = r >> 6, d = r & 63;
  const float* W = (p == 0) ? Wq : (p == 1) ? Wk : Wv;
  WT[p * 65536 + d * 1024 + kk] = f2bf(W[r]);
}

// ---------------- kernel 2: fused projections (LDS-free, barrier-free) -----
// One wave owns a 16-row x 64-col output tile; K=1024 streamed in 32-chunks.
// p=0: qs[b,s,d]  = (q@Wq+bq) * m[b,s]/8 * log2(e)   (row-major, bf16)
// p=1: kh[b,s,d]  = k@Wk+bk                           (row-major)
// p=2: vhT[b,d,s] = (v@Wv+bv)^T  (same loads, swapped MFMA operand roles)
__global__ __launch_bounds__(256) void proj_kernel(
    const float* __restrict__ xq, const float* __restrict__ xk,
    const float* __restrict__ xv, const float* __restrict__ mmask,
    const float* __restrict__ bq, const float* __restrict__ bk,
    const float* __restrict__ bv, const unsigned short* __restrict__ WT,
    unsigned short* __restrict__ qs, unsigned short* __restrict__ khh,
    unsigned short* __restrict__ vhT) {
  const int t = threadIdx.x;
  const int w = t >> 6, ln = t & 63;
  const int lr = ln & 15, quad = ln >> 4;

  const int gw = blockIdx.x * 4 + w;     // global wave id, 0..3071
  const int p = gw >> 10;                // blocks are p-uniform (1024%4==0)
  const int row0 = (gw & 1023) * 16;     // flat (b,s) row in [0,16384)

  const float* X = (p == 0) ? xq : (p == 1) ? xk : xv;
  // A-side (X): lane (lr,quad) streams 8 contiguous fp32 of row row0+lr
  const float* Xl = X + (size_t)(row0 + lr) * 1024 + quad * 8;
  // B-side (W): lane (lr,quad) streams 8 contiguous bf16 of WT row ct*16+lr
  const unsigned short* Wl = WT + p * 65536 + (size_t)lr * 1024 + quad * 8;

  float4v acc[4];
#pragma unroll
  for (int i = 0; i < 4; ++i) acc[i] = (float4v){0.f, 0.f, 0.f, 0.f};

  for (int kc = 0; kc < 8; ++kc) {       // K=1024, 128 per kc
#pragma unroll
    for (int ks = 0; ks < 4; ++ks) {     // 32 per ks
      const int ko = kc * 128 + ks * 32;
      float4v x0 = *(const float4v*)(Xl + ko);
      float4v x1 = *(const float4v*)(Xl + ko + 4);
      short8 wf0 = *(const short8*)(Wl + ko);
      short8 wf1 = *(const short8*)(Wl + 16384 + ko);
      short8 wf2 = *(const short8*)(Wl + 32768 + ko);
      short8 wf3 = *(const short8*)(Wl + 49152 + ko);
      short8 xf;
#pragma unroll
      for (int j = 0; j < 4; ++j) {
        xf[j] = (short)f2bf(x0[j]);
        xf[4 + j] = (short)f2bf(x1[j]);
      }
      if (p < 2) {                       // D[s][d] = X @ W
        acc[0] = __builtin_amdgcn_mfma_f32_16x16x32_bf16(xf, wf0, acc[0], 0, 0, 0);
        acc[1] = __builtin_amdgcn_mfma_f32_16x16x32_bf16(xf, wf1, acc[1], 0, 0, 0);
        acc[2] = __builtin_amdgcn_mfma_f32_16x16x32_bf16(xf, wf2, acc[2], 0, 0, 0);
        acc[3] = __builtin_amdgcn_mfma_f32_16x16x32_bf16(xf, wf3, acc[3], 0, 0, 0);
      } else {                           // D[d][s] = WT @ X^T
        acc[0] = __builtin_amdgcn_mfma_f32_16x16x32_bf16(wf0, xf, acc[0], 0, 0, 0);
        acc[1] = __builtin_amdgcn_mfma_f32_16x16x32_bf16(wf1, xf, acc[1], 0, 0, 0);
        acc[2] = __builtin_amdgcn_mfma_f32_16x16x32_bf16(wf2, xf, acc[2], 0, 0, 0);
        acc[3] = __builtin_amdgcn_mfma_f32_16x16x32_bf16(wf3, xf, acc[3], 0, 0, 0);
      }
    }
  }

  // epilogues; C/D layout: col = lr, row = quad*4 + r
  if (p == 0) {
    const float L2E8 = 1.4426950408889634f * 0.125f;  // log2(e)/sqrt(64)
#pragma unroll
    for (int r = 0; r < 4; ++r) {
      int sg = row0 + quad * 4 + r;
      float mv = mmask[sg] * L2E8;
#pragma unroll
      for (int ct = 0; ct < 4; ++ct) {
        int d = ct * 16 + lr;
        qs[(size_t)sg * 64 + d] = f2bf((acc[ct][r] + bq[d]) * mv);
      }
    }
  } else if (p == 1) {
#pragma unroll
    for (int r = 0; r < 4; ++r) {
      int sg = row0 + quad * 4 + r;
#pragma unroll
      for (int ct = 0; ct < 4; ++ct) {
        int d = ct * 16 + lr;
        khh[(size_t)sg * 64 + d] = f2bf(acc[ct][r] + bk[d]);
      }
    }
  } else {
    // acc[ct]: D rows = d (tile ct), cols = s (the wave's 16 X-rows)
    int b = row0 >> 12, sloc = row0 & 4095;
#pragma unroll
    for (int ct = 0; ct < 4; ++ct)
#pragma unroll
      for (int r = 0; r < 4; ++r) {
        int d = ct * 16 + quad * 4 + r;
        vhT[(size_t)b * 64 * 4096 + (size_t)d * 4096 + sloc + lr] =
            f2bf(acc[ct][r] + bv[d]);
      }
  }
}

// ---------------- kernel 3: split-K flash attention (prefetched) ------------
// grid = SPLITS * B * (S/64); block = 4 waves, each wave owns 16 q-rows.
// Each block processes 1024 keys (16 tiles of 64). No max subtraction
// (scores statically bounded) -> additive (O,L) partials per split.
#define SPLITS 4
__global__ __launch_bounds__(256) void attn_split(
    const unsigned short* __restrict__ qs, const unsigned short* __restrict__ khh,
    const unsigned short* __restrict__ vhT, float* __restrict__ O_part,
    float* __restrict__ L_part) {
  constexpr int LDSTR = 88;
  __shared__ __align__(16) unsigned short Ks[64 * LDSTR];       // [key][d]
  __shared__ __align__(16) unsigned short Vs[64 * LDSTR];       // [d][key]
  __shared__ __align__(16) unsigned short Ps[4 * 16 * LDSTR];   // per-wave P [q][key]

  const int split = blockIdx.x >> 8;
  const int rest  = blockIdx.x & 255;
  const int b = rest >> 6;
  const int s0 = (rest & 63) * 64;
  const int t = threadIdx.x, w = t >> 6, ln = t & 63;
  const int lr = ln & 15, quad = ln >> 4;

  // Q A-fragments, held in registers for the whole kernel
  const size_t qrow = (size_t)(b * 4096 + s0 + w * 16 + lr) * 64;
  short8 qf0 = *(const short8*)&qs[qrow + quad * 8];
  short8 qf1 = *(const short8*)&qs[qrow + 32 + quad * 8];

  float Lacc[4] = {0.f, 0.f, 0.f, 0.f};
  float4v O[4];
#pragma unroll
  for (int i = 0; i < 4; ++i) O[i] = (float4v){0.f, 0.f, 0.f, 0.f};

  const int srow = t >> 3, scol = (t & 7) * 8;
  const unsigned short* Kg = khh + (size_t)b * 4096 * 64;
  const unsigned short* Vg = vhT + (size_t)b * 64 * 4096;
  unsigned short* Pw = Ps + w * 16 * LDSTR;

  uint4v kr[2], vr[2];                // prefetch registers

#define ISSUE_KV(kt_)                                                       \
  {                                                                         \
    const int k0_ = split * 1024 + (kt_) * 64;                              \
    _Pragma("unroll") for (int ps = 0; ps < 2; ++ps) {                      \
      const int rr = srow + ps * 32;                                        \
      kr[ps] = *(const uint4v*)&Kg[(size_t)(k0_ + rr) * 64 + scol];         \
      vr[ps] = *(const uint4v*)&Vg[(size_t)rr * 4096 + k0_ + scol];         \
    }                                                                       \
  }

  ISSUE_KV(0);
  for (int kt = 0; kt < 16; ++kt) {
#pragma unroll
    for (int ps = 0; ps < 2; ++ps) {
      const int rr = srow + ps * 32;
      *(uint4v*)&Ks[rr * LDSTR + scol] = kr[ps];
      *(uint4v*)&Vs[rr * LDSTR + scol] = vr[ps];
    }
    __syncthreads();
    if (kt < 15) ISSUE_KV(kt + 1);    // overlap next tile's loads with compute

    // S = Q K^T: 16 q-rows x 64 keys per wave
    float4v sc[4];
#pragma unroll
    for (int ct = 0; ct < 4; ++ct) {
      sc[ct] = (float4v){0.f, 0.f, 0.f, 0.f};
      short8 kf0 = *(const short8*)&Ks[(ct * 16 + lr) * LDSTR + quad * 8];
      short8 kf1 = *(const short8*)&Ks[(ct * 16 + lr) * LDSTR + 32 + quad * 8];
      sc[ct] = __builtin_amdgcn_mfma_f32_16x16x32_bf16(qf0, kf0, sc[ct], 0, 0, 0);
      sc[ct] = __builtin_amdgcn_mfma_f32_16x16x32_bf16(qf1, kf1, sc[ct], 0, 0, 0);
    }

    // P = exp2(S), accumulate per-lane row partials (no shuffles, no rescale)
#pragma unroll
    for (int ct = 0; ct < 4; ++ct)
#pragma unroll
      for (int r = 0; r < 4; ++r) {
        float pv = exp2f(sc[ct][r]);
        Lacc[r] += pv;
        Pw[(quad * 4 + r) * LDSTR + ct * 16 + lr] = f2bf(pv);
      }

    __asm__ volatile("s_waitcnt lgkmcnt(0)" ::: "memory");

    short8 pf0 = *(const short8*)&Pw[lr * LDSTR + quad * 8];
    short8 pf1 = *(const short8*)&Pw[lr * LDSTR + 32 + quad * 8];
#pragma unroll
    for (int dt = 0; dt < 4; ++dt) {
      short8 vf0 = *(const short8*)&Vs[(dt * 16 + lr) * LDSTR + quad * 8];
      short8 vf1 = *(const short8*)&Vs[(dt * 16 + lr) * LDSTR + 32 + quad * 8];
      O[dt] = __builtin_amdgcn_mfma_f32_16x16x32_bf16(pf0, vf0, O[dt], 0, 0, 0);
      O[dt] = __builtin_amdgcn_mfma_f32_16x16x32_bf16(pf1, vf1, O[dt], 0, 0, 0);
    }
    __syncthreads();
  }
#undef ISSUE_KV

  // reduce L over the 16 lanes of each quad (once per kernel, not per tile)
#pragma unroll
  for (int r = 0; r < 4; ++r) {
    float s = Lacc[r];
    s += __shfl_xor(s, 1);
    s += __shfl_xor(s, 2);
    s += __shfl_xor(s, 4);
    s += __shfl_xor(s, 8);
    Lacc[r] = s;
  }

  // store partials; C/D layout: col=lr (d), row=quad*4+r (q-row)
#pragma unroll
  for (int r = 0; r < 4; ++r) {
    int prow = b * 4096 + s0 + w * 16 + quad * 4 + r;
    size_t obase = ((size_t)split * 16384 + prow) * 64;
#pragma unroll
    for (int dt = 0; dt < 4; ++dt)
      O_part[obase + dt * 16 + lr] = O[dt][r];
    if (lr == 0) L_part[(size_t)split * 16384 + prow] = Lacc[r];
  }
}

// ---------------- kernel 4: split-K combine ---------------------------------
__global__ __launch_bounds__(256) void attn_reduce(
    const float* __restrict__ O_part, const float* __restrict__ L_part,
    float* __restrict__ out) {
  size_t idx = (size_t)blockIdx.x * 256 + threadIdx.x;  // over 16384*64
  size_t row = idx >> 6;
  float l = L_part[row] + L_part[16384 + row] + L_part[2 * 16384 + row] +
            L_part[3 * 16384 + row];
  float o = O_part[idx] + O_part[idx + (size_t)16384 * 64] +
            O_part[idx + (size_t)2 * 16384 * 64] +
            O_part[idx + (size_t)3 * 16384 * 64];
  out[idx] = o / l;
}

// ---------------- launch ----------------------------------------------------
extern "C" void kernel_launch(void* const* d_in, const int* in_sizes, int n_in,
                              void* d_out, int out_size, void* d_ws, size_t ws_size,
                              hipStream_t stream) {
  const float* q  = (const float*)d_in[0];
  const float* k  = (const float*)d_in[1];
  const float* v  = (const float*)d_in[2];
  const float* m  = (const float*)d_in[3];
  const float* Wq = (const float*)d_in[4];
  const float* bq = (const float*)d_in[5];
  const float* Wk = (const float*)d_in[6];
  const float* bk = (const float*)d_in[7];
  const float* Wv = (const float*)d_in[8];
  const float* bv = (const float*)d_in[9];
  float* out = (float*)d_out;

  unsigned short* ws16 = (unsigned short*)d_ws;
  unsigned short* WT  = ws16;                     // 3*65536 u16
  unsigned short* qs  = WT + 3 * 65536;           // 16384*64
  unsigned short* kh  = qs + 16384 * 64;          // 16384*64
  unsigned short* vhT = kh + 16384 * 64;          // 4*64*4096
  float* O_part = (float*)(vhT + 16384 * 64);     // SPLITS*16384*64 fp32 (16.8MB)
  float* L_part = O_part + (size_t)SPLITS * 16384 * 64;  // SPLITS*16384 fp32

  transpose_w<<<dim3(768), dim3(256), 0, stream>>>(Wq, Wk, Wv, WT);
  proj_kernel<<<dim3(768), dim3(256), 0, stream>>>(q, k, v, m, bq, bk, bv, WT,
                                                   qs, kh, vhT);
  attn_split<<<dim3(SPLITS * 256), dim3(256), 0, stream>>>(qs, kh, vhT,
                                                           O_part, L_part);
  attn_reduce<<<dim3(4096), dim3(256), 0, stream>>>(O_part, L_part, out);
}